// Round 1
// 1302.397 us; speedup vs baseline: 1.4330x; 1.4330x over previous
//
#include <hip/hip_runtime.h>

// Problem: B=4, C=64, H=W=256, 4x4 tiles of 64, dynamic 3x3 conv 64->32 per tile.
// Inputs f32 (proven: bf16 decode of inputs NaN-poisoned round 1).
// Output f32. h (conv1 output) staged in f32 inside d_out planes (b*96 + c), c<64,
// then overwritten by the feature passthrough at the end of the launch.
//
// v2 conv core: LDS-pipe analysis showed the old kernel spent ~48 of ~64 LDS
// cycles per k-step on ds_read_b128 weight *broadcasts* (VALUBusy 26.7% matched
// an LDS-pipe-bound model). Weights now bypass LDS entirely: pre-transposed to
// [ocg][ic][k][oc16] and read via wave-uniform pointers (s_load / same-addr VMEM).
// Inputs read as aligned ds_read_b64 pairs (stride-36 rows, even col pairs).
// 4 px/thread (32x32 spatial tile, 2 cols x 2 row-groups), 16 oc/block.

// ---------------------------------------------------------------------------
// transpose rw1 [64oc][64ic][3][3] -> rw1t [4ocg][64ic][9k][16oc]
// ---------------------------------------------------------------------------
__global__ __launch_bounds__(256) void transp_rw1_k(
    const float* __restrict__ rw1, float* __restrict__ rt)
{
    int idx = blockIdx.x * 256 + threadIdx.x;
    if (idx >= 36864) return;
    int ocg = idx / 9216;
    int r   = idx - ocg * 9216;
    int ic  = r / 144;
    int r2  = r - ic * 144;
    int k   = r2 >> 4;
    int o   = r2 & 15;
    rt[idx] = rw1[(((size_t)(ocg * 16 + o) * 64 + ic) * 9) + k];
}

// ---------------------------------------------------------------------------
// Generic 3x3 conv, 16 oc per block, 4 px per thread (2 cols x 2 row groups).
// Block: 256 threads = 16x16, spatial tile 32x32.
// MODE 0: conv1  — in=feature, wt=rw1t, bias=rb1, leaky ReLU ->
//                  h planes in d_out at (b*96 + oc), oc<64
// MODE 1: dyncnv — in=feature, wt=wb (fc3 wrote transposed layout),
//                  bias from wb row tail -> d_out planes (b*96+64+oc), oc<32
// ---------------------------------------------------------------------------
template <int MODE>
__global__ __launch_bounds__(256, 3) void conv3x3_v2(
    const float* __restrict__ in,    // feature f32 [4][64][256][256]
    const float* __restrict__ wt,    // transposed weights (see above)
    const float* __restrict__ bbf,   // MODE0: rb1[64]; MODE1: wb (bias at row tail)
    float* __restrict__ outb)        // d_out f32 [4][96][256][256]
{
    __shared__ float sIn[8 * 34 * 36];   // 8 ic x 34 rows x (34 cols + 2 pad), stride 36 (even!)

    const int bx = blockIdx.x, by = blockIdx.y, bz = blockIdx.z;
    int b, ocg;
    if (MODE == 0) { b = bz >> 2; ocg = bz & 3; }
    else           { b = bz >> 1; ocg = bz & 1; }
    const int tid = threadIdx.x;
    const int tx = tid & 15, ty = tid >> 4;
    const int x0 = bx * 32, y0 = by * 32;

    int bt = 0;
    const float* wbase;
    if (MODE == 0) {
        wbase = wt + ocg * 9216;
    } else {
        bt = b * 16 + (by >> 1) * 4 + (bx >> 1);      // 64x64 weight-tile index
        wbase = wt + (size_t)bt * 18464 + ocg * 9216;
    }

    float acc[2][2][16];   // [row group][px][oc]
#pragma unroll
    for (int rg = 0; rg < 2; ++rg)
#pragma unroll
        for (int p = 0; p < 2; ++p)
#pragma unroll
            for (int oc = 0; oc < 16; ++oc) acc[rg][p][oc] = 0.f;

    for (int cc = 0; cc < 8; ++cc) {   // 8 chunks of 8 input channels
        __syncthreads();
        // stage 8 ic x 34 x 34 halo tile (global zero-pad), LDS row stride 36
        for (int idx = tid; idx < 8 * 34 * 34; idx += 256) {
            int ic  = idx / 1156;
            int rem = idx - ic * 1156;
            int r   = rem / 34;
            int c   = rem - r * 34;
            int gy = y0 + r - 1, gx = x0 + c - 1;
            float v = 0.f;
            if ((unsigned)gy < 256u && (unsigned)gx < 256u)
                v = in[(((size_t)b * 64 + cc * 8 + ic) * 256 + gy) * 256 + gx];
            sIn[ic * 1224 + r * 36 + c] = v;
        }
        __syncthreads();

        const float* wc = wbase + cc * 8 * 144;
        for (int ic = 0; ic < 8; ++ic) {
            const float* sI = &sIn[ic * 1224 + ty * 36 + 2 * tx];
            const float* wp = wc + ic * 144;     // wave-uniform -> scalar loads
#pragma unroll
            for (int kh = 0; kh < 3; ++kh) {
                float w[3][16];
#pragma unroll
                for (int kw = 0; kw < 3; ++kw) {
                    *(float4*)&w[kw][0]  = *(const float4*)&wp[(kh * 3 + kw) * 16 + 0];
                    *(float4*)&w[kw][4]  = *(const float4*)&wp[(kh * 3 + kw) * 16 + 4];
                    *(float4*)&w[kw][8]  = *(const float4*)&wp[(kh * 3 + kw) * 16 + 8];
                    *(float4*)&w[kw][12] = *(const float4*)&wp[(kh * 3 + kw) * 16 + 12];
                }
#pragma unroll
                for (int rg = 0; rg < 2; ++rg) {
                    const float* rp = sI + (rg * 16 + kh) * 36;
                    float2 a  = *(const float2*)&rp[0];   // cols 2tx, 2tx+1 (8B aligned)
                    float2 bq = *(const float2*)&rp[2];   // cols 2tx+2, 2tx+3
                    float iv[4] = {a.x, a.y, bq.x, bq.y};
#pragma unroll
                    for (int kw = 0; kw < 3; ++kw) {
#pragma unroll
                        for (int oc = 0; oc < 16; ++oc) {
                            acc[rg][0][oc] += iv[kw]     * w[kw][oc];
                            acc[rg][1][oc] += iv[kw + 1] * w[kw][oc];
                        }
                    }
                }
            }
        }
    }

#pragma unroll
    for (int rg = 0; rg < 2; ++rg) {
        const int gy = y0 + ty + rg * 16;
#pragma unroll
        for (int oc = 0; oc < 16; ++oc) {
            float bv;
            int plane;
            if (MODE == 0) {
                bv = bbf[ocg * 16 + oc];
                plane = b * 96 + ocg * 16 + oc;
            } else {
                bv = bbf[(size_t)bt * 18464 + 18432 + ocg * 16 + oc];
                plane = b * 96 + 64 + ocg * 16 + oc;
            }
            float v0 = acc[rg][0][oc] + bv;
            float v1 = acc[rg][1][oc] + bv;
            if (MODE == 0) {
                v0 = (v0 >= 0.f) ? v0 : 0.2f * v0;   // leaky relu
                v1 = (v1 >= 0.f) ? v1 : 0.2f * v1;
            }
            size_t o = (((size_t)plane) * 256 + gy) * 256 + x0 + 2 * tx;
            float2 st = {v0, v1};
            *(float2*)&outb[o] = st;
        }
    }
}

// ---------------------------------------------------------------------------
// conv2: 64 -> 1 channel, 3x3 pad 1, + bias + tanh. Reads f32 h from d_out
// planes (b*96 + ic). (Unchanged this round — ~50 µs, revisit later.)
// ---------------------------------------------------------------------------
__global__ __launch_bounds__(256) void conv2_tanh_k(
    const float* __restrict__ hin,   // d_out f32, h at planes b*96 + 0..63
    const float* __restrict__ rw2,   // [1][64][3][3]
    const float* __restrict__ rb2,   // [1]
    float* __restrict__ ad)          // adaptive f32 [4][256][256]
{
    __shared__ float sIn[16 * 18 * 35];
    __shared__ float sW[144];
    const int bx = blockIdx.x, by = blockIdx.y, b = blockIdx.z;
    const int tid = threadIdx.x;
    const int tx = tid & 15, ty = tid >> 4;
    const int x0 = bx * 32, y0 = by * 16;
    float a0 = 0.f, a1 = 0.f;

    for (int cc = 0; cc < 4; ++cc) {
        __syncthreads();
        for (int idx = tid; idx < 16 * 18 * 34; idx += 256) {
            int ic = idx / 612;
            int rem = idx - ic * 612;
            int row = rem / 34;
            int col = rem - row * 34;
            int gy = y0 + row - 1, gx = x0 + col - 1;
            float v = 0.f;
            if ((unsigned)gy < 256u && (unsigned)gx < 256u)
                v = hin[(((size_t)b * 96 + cc * 16 + ic) * 256 + gy) * 256 + gx];
            sIn[ic * 630 + row * 35 + col] = v;
        }
        if (tid < 144) sW[tid] = rw2[cc * 144 + tid];
        __syncthreads();

        for (int ic = 0; ic < 16; ++ic) {
            const float* sI = &sIn[ic * 630 + ty * 35 + tx];
            const float* sWi = &sW[ic * 9];
#pragma unroll
            for (int k = 0; k < 9; ++k) {
                const int kh = k / 3, kw = k - kh * 3;
                float w = sWi[k];
                a0 += sI[kh * 35 + kw] * w;
                a1 += sI[kh * 35 + kw + 16] * w;
            }
        }
    }
    float bias = rb2[0];
    size_t o = ((size_t)b * 256 + y0 + ty) * 256 + x0 + tx;
    ad[o] = tanhf(a0 + bias);
    ad[o + 16] = tanhf(a1 + bias);
}

// ---------------------------------------------------------------------------
// Adaptive-avg gram: per (bt, p, q) average the 66->32 window over the padded
// 66x66 tile of `adaptive`. Denominator counts pad zeros (matches reference).
// ---------------------------------------------------------------------------
__global__ __launch_bounds__(256) void gram_pool_k(
    const float* __restrict__ adaptive, float* __restrict__ gram)
{
    int idx = blockIdx.x * 256 + threadIdx.x;  // 64*1024
    int bt = idx >> 10;
    int pq = idx & 1023;
    int p = pq >> 5, q = pq & 31;
    int b = bt >> 4, t = bt & 15;
    int ti = t >> 2, tj = t & 3;
    int sp = (p * 33) >> 4, ep = ((p + 1) * 33 + 15) >> 4;  // 66/32 == 33/16
    int sq = (q * 33) >> 4, eq = ((q + 1) * 33 + 15) >> 4;
    float s = 0.f;
    for (int hh = sp; hh < ep; ++hh) {
        int gy = ti * 64 + hh - 1;
        if ((unsigned)gy >= 256u) continue;
        for (int w = sq; w < eq; ++w) {
            int gx = tj * 64 + w - 1;
            if ((unsigned)gx < 256u) s += adaptive[((size_t)b * 256 + gy) * 256 + gx];
        }
    }
    gram[idx] = s / (float)((ep - sp) * (eq - sq));
}

// ---------------------------------------------------------------------------
// FC: C[64,N] = act(A[64,K] @ B[K,N] + bias). All f32.
// Block computes a 64x64 tile of C; threads 16x16, 4x4 per thread.
// trans=1 (fc3): scatter the first 18432 cols of each row into the
// [ocg2][ic64][k9][oc16] layout conv3x3_v2<1> consumes; bias cols stay put.
// ---------------------------------------------------------------------------
__global__ __launch_bounds__(256) void fc_gemm_k(
    const float* __restrict__ A, const float* __restrict__ Bm,
    const float* __restrict__ bias, float* __restrict__ Cm,
    int K, int N, int act, int trans)
{
    __shared__ float As[16][68];  // [kk][m]
    __shared__ float Bs[16][64];  // [kk][n]
    const int n0 = blockIdx.x * 64;
    const int tid = threadIdx.x;
    const int tx = tid & 15, ty = tid >> 4;
    float acc[4][4];
#pragma unroll
    for (int i = 0; i < 4; ++i)
#pragma unroll
        for (int j = 0; j < 4; ++j) acc[i][j] = 0.f;

    const int mA = tid >> 2, kA = (tid & 3) * 4;
    const int kB = tid >> 4, nB = (tid & 15) * 4;

    for (int k0 = 0; k0 < K; k0 += 16) {
        __syncthreads();
        float4 av = *(const float4*)&A[(size_t)mA * K + k0 + kA];
        As[kA + 0][mA] = av.x;
        As[kA + 1][mA] = av.y;
        As[kA + 2][mA] = av.z;
        As[kA + 3][mA] = av.w;
        {
            int gn = n0 + nB;
            const float* bp = Bm + (size_t)(k0 + kB) * N + gn;
            float b0 = 0.f, b1 = 0.f, b2 = 0.f, b3 = 0.f;
            if (gn + 3 < N) {
                float4 u = *(const float4*)bp;
                b0 = u.x; b1 = u.y; b2 = u.z; b3 = u.w;
            } else {
                if (gn < N)     b0 = bp[0];
                if (gn + 1 < N) b1 = bp[1];
                if (gn + 2 < N) b2 = bp[2];
            }
            Bs[kB][nB + 0] = b0; Bs[kB][nB + 1] = b1;
            Bs[kB][nB + 2] = b2; Bs[kB][nB + 3] = b3;
        }
        __syncthreads();
#pragma unroll
        for (int kk = 0; kk < 16; ++kk) {
            float4 a = *(const float4*)&As[kk][ty * 4];
            float4 bb = *(const float4*)&Bs[kk][tx * 4];
            acc[0][0] += a.x * bb.x; acc[0][1] += a.x * bb.y; acc[0][2] += a.x * bb.z; acc[0][3] += a.x * bb.w;
            acc[1][0] += a.y * bb.x; acc[1][1] += a.y * bb.y; acc[1][2] += a.y * bb.z; acc[1][3] += a.y * bb.w;
            acc[2][0] += a.z * bb.x; acc[2][1] += a.z * bb.y; acc[2][2] += a.z * bb.z; acc[2][3] += a.z * bb.w;
            acc[3][0] += a.w * bb.x; acc[3][1] += a.w * bb.y; acc[3][2] += a.w * bb.z; acc[3][3] += a.w * bb.w;
        }
    }
#pragma unroll
    for (int i = 0; i < 4; ++i) {
        int m = ty * 4 + i;
#pragma unroll
        for (int j = 0; j < 4; ++j) {
            int n = n0 + tx * 4 + j;
            if (n < N) {
                float v = acc[i][j] + bias[n];
                if (act) v = fmaxf(v, 0.f);
                int col = n;
                if (trans && n < 18432) {
                    int oc  = n / 576;
                    int rem = n - oc * 576;          // ic*9 + k
                    col = (oc >> 4) * 9216 + rem * 16 + (oc & 15);
                }
                Cm[(size_t)m * N + col] = v;
            }
        }
    }
}

// ---------------------------------------------------------------------------
// feature (f32) -> f32 passthrough into output channels 0..63 (plane remap).
// Runs LAST: overwrites the h staging planes.
// ---------------------------------------------------------------------------
__global__ __launch_bounds__(256) void copy_feat_k(
    const float4* __restrict__ f, float4* __restrict__ o)
{
    int idx = blockIdx.x * 256 + threadIdx.x;  // 4,194,304 float4
    int plane = idx >> 14;                     // b*64 + c (16384 f4 / plane)
    int off = idx & 16383;
    int b = plane >> 6, c = plane & 63;
    o[((size_t)(b * 96 + c)) * 16384 + off] = f[idx];
}

extern "C" void kernel_launch(void* const* d_in, const int* in_sizes, int n_in,
                              void* d_out, int out_size, void* d_ws, size_t ws_size,
                              hipStream_t stream) {
    const float* feature = (const float*)d_in[0];
    const float* rw1 = (const float*)d_in[1];
    const float* rb1 = (const float*)d_in[2];
    const float* rw2 = (const float*)d_in[3];
    const float* rb2 = (const float*)d_in[4];
    const float* fw1 = (const float*)d_in[5];
    const float* fb1 = (const float*)d_in[6];
    const float* fw2 = (const float*)d_in[7];
    const float* fb2 = (const float*)d_in[8];
    const float* fw3 = (const float*)d_in[9];
    const float* fb3 = (const float*)d_in[10];
    float* out = (float*)d_out;

    // Workspace layout (~7.1 MB):
    float* adaptive = (float*)d_ws;                   // 262,144 f32
    float* gram = adaptive + 262144;                  // 65,536 f32
    float* g1 = gram + 65536;                         // 131,072 f32
    float* g2 = g1 + 131072;                          // 131,072 f32
    float* wb = g2 + 131072;                          // 1,181,696 f32
    float* rw1t = g1;                                 // alias: dead before fc1 writes g1

    // 0. transpose rw1 -> [4ocg][64ic][9k][16oc] (rw1t aliases g1; conv1 reads
    //    it before fc1 overwrites g1 — stream-ordered, safe)
    transp_rw1_k<<<dim3(144), 256, 0, stream>>>(rw1, rw1t);
    // 1. conv1 + leaky relu -> h staged in d_out planes (b*96 + 0..63)
    conv3x3_v2<0><<<dim3(8, 8, 16), 256, 0, stream>>>(feature, rw1t, rb1, out);
    // 2. conv2 + tanh -> adaptive (reads h from d_out)
    conv2_tanh_k<<<dim3(8, 16, 4), 256, 0, stream>>>(out, rw2, rb2, adaptive);
    // 3. adaptive-avg gram -> gram [64][1024]
    gram_pool_k<<<dim3(256), 256, 0, stream>>>(adaptive, gram);
    // 4-6. FC stack -> wb [64][18464]; fc3 writes weight cols pre-transposed
    fc_gemm_k<<<dim3(32), 256, 0, stream>>>(gram, fw1, fb1, g1, 1024, 2048, 1, 0);
    fc_gemm_k<<<dim3(32), 256, 0, stream>>>(g1, fw2, fb2, g2, 2048, 2048, 1, 0);
    fc_gemm_k<<<dim3(289), 256, 0, stream>>>(g2, fw3, fb3, wb, 2048, 18464, 0, 1);
    // 7. dynamic per-tile conv -> out channels 64..95 (+ bias, spliced)
    conv3x3_v2<1><<<dim3(8, 8, 8), 256, 0, stream>>>(feature, wb, wb, out);
    // 8. passthrough: feature -> out channels 0..63 (overwrites h staging)
    copy_feat_k<<<dim3(16384), 256, 0, stream>>>((const float4*)feature, (float4*)out);
}